// Round 3
// baseline (548.939 us; speedup 1.0000x reference)
//
#include <hip/hip_runtime.h>
#include <hip/hip_bf16.h>

typedef __bf16 bf16_t;
typedef bf16_t bf16x8 __attribute__((ext_vector_type(8)));
typedef float floatx4 __attribute__((ext_vector_type(4)));

#define HID 1024
#define HEADS 16
#define HD 64
#define BATCH 4
#define SEQ 2048
#define MTOT (BATCH * SEQ) /* 8192 */

// Load 8 contiguous elements as bf16x8; fp32 source converts on the fly.
__device__ inline bf16x8 load8(const bf16_t* p) { return *(const bf16x8*)p; }
__device__ inline bf16x8 load8(const float* p) {
    floatx4 x = *(const floatx4*)p;
    floatx4 y = *(const floatx4*)(p + 4);
    bf16x8 r;
    r[0] = (bf16_t)x[0]; r[1] = (bf16_t)x[1];
    r[2] = (bf16_t)x[2]; r[3] = (bf16_t)x[3];
    r[4] = (bf16_t)y[0]; r[5] = (bf16_t)y[1];
    r[6] = (bf16_t)y[2]; r[7] = (bf16_t)y[3];
    return r;
}
// hi/lo split: x ~= hi + lo, residual ~2^-17 relative.
__device__ inline void split8(const float* p, bf16x8& hi, bf16x8& lo) {
    floatx4 x = *(const floatx4*)p;
    floatx4 y = *(const floatx4*)(p + 4);
    float v[8] = {x[0], x[1], x[2], x[3], y[0], y[1], y[2], y[3]};
#pragma unroll
    for (int j = 0; j < 8; ++j) {
        hi[j] = (bf16_t)v[j];
        lo[j] = (bf16_t)(v[j] - (float)hi[j]);
    }
}

// ---------------------------------------------------------------------------
// GEMM: Out = A @ W^T + bias      (A: [M,K] TA, W: [N,K] fp32, bias fp32)
// MODE 0: store to [B][H][S][D]  (m = b*SEQ+s, n = h*HD+d)   -- Q/K/V
// MODE 1: store to flat [M, N]                                -- final
// SPLIT=1 (requires TA=float): bf16 hi+lo split of A and W, 3 MFMAs/tile
//   (hh + lh + hl) -> fp32-grade product precision for the Q/K logit path.
// 128x128 tile, BK=32, 256 thr (4 waves 2x2), mfma 16x16x32 bf16.
// ---------------------------------------------------------------------------
template <int MODE, int SPLIT, typename TA, typename TOut>
__global__ __launch_bounds__(256) void gemm_bt(
    const TA* __restrict__ A, const float* __restrict__ W,
    const float* __restrict__ bias, TOut* __restrict__ Out)
{
    __shared__ bf16_t As[SPLIT + 1][128][40];
    __shared__ bf16_t Bs[SPLIT + 1][128][40];

    const int tid  = threadIdx.x;
    const int m0   = blockIdx.y * 128;
    const int n0   = blockIdx.x * 128;
    const int wave = tid >> 6;
    const int lane = tid & 63;
    const int quad = lane >> 4;
    const int l16  = lane & 15;
    const int wm   = (wave >> 1) * 64;
    const int wn   = (wave & 1) * 64;
    const int trow = tid >> 1;          // 0..127
    const int tcol = (tid & 1) * 16;    // 0 or 16

    const TA*    aptr = A + (size_t)(m0 + trow) * HID + tcol;
    const float* bptr = W + (size_t)(n0 + trow) * HID + tcol;

    floatx4 acc[4][4];
    const floatx4 zero4 = {0.f, 0.f, 0.f, 0.f};
#pragma unroll
    for (int mt = 0; mt < 4; ++mt)
#pragma unroll
        for (int nt = 0; nt < 4; ++nt) acc[mt][nt] = zero4;

    for (int k0 = 0; k0 < HID; k0 += 32) {
        if constexpr (SPLIT) {
            bf16x8 ah0, al0, ah1, al1, bh0, bl0, bh1, bl1;
            split8(aptr, ah0, al0);
            split8(aptr + 8, ah1, al1);
            split8(bptr, bh0, bl0);
            split8(bptr + 8, bh1, bl1);
            __syncthreads();
            *(bf16x8*)&As[0][trow][tcol]     = ah0;
            *(bf16x8*)&As[0][trow][tcol + 8] = ah1;
            *(bf16x8*)&As[1][trow][tcol]     = al0;
            *(bf16x8*)&As[1][trow][tcol + 8] = al1;
            *(bf16x8*)&Bs[0][trow][tcol]     = bh0;
            *(bf16x8*)&Bs[0][trow][tcol + 8] = bh1;
            *(bf16x8*)&Bs[1][trow][tcol]     = bl0;
            *(bf16x8*)&Bs[1][trow][tcol + 8] = bl1;
            __syncthreads();

            bf16x8 afh[4], afl[4], bfh[4], bfl[4];
#pragma unroll
            for (int t = 0; t < 4; ++t) {
                afh[t] = *(const bf16x8*)&As[0][wm + t * 16 + l16][quad * 8];
                afl[t] = *(const bf16x8*)&As[1][wm + t * 16 + l16][quad * 8];
                bfh[t] = *(const bf16x8*)&Bs[0][wn + t * 16 + l16][quad * 8];
                bfl[t] = *(const bf16x8*)&Bs[1][wn + t * 16 + l16][quad * 8];
            }
#pragma unroll
            for (int mt = 0; mt < 4; ++mt)
#pragma unroll
                for (int nt = 0; nt < 4; ++nt) {
                    acc[mt][nt] = __builtin_amdgcn_mfma_f32_16x16x32_bf16(
                        afh[mt], bfh[nt], acc[mt][nt], 0, 0, 0);
                    acc[mt][nt] = __builtin_amdgcn_mfma_f32_16x16x32_bf16(
                        afl[mt], bfh[nt], acc[mt][nt], 0, 0, 0);
                    acc[mt][nt] = __builtin_amdgcn_mfma_f32_16x16x32_bf16(
                        afh[mt], bfl[nt], acc[mt][nt], 0, 0, 0);
                }
        } else {
            bf16x8 av0 = load8(aptr);
            bf16x8 av1 = load8(aptr + 8);
            bf16x8 bv0 = load8(bptr);
            bf16x8 bv1 = load8(bptr + 8);
            __syncthreads();
            *(bf16x8*)&As[0][trow][tcol]     = av0;
            *(bf16x8*)&As[0][trow][tcol + 8] = av1;
            *(bf16x8*)&Bs[0][trow][tcol]     = bv0;
            *(bf16x8*)&Bs[0][trow][tcol + 8] = bv1;
            __syncthreads();

            bf16x8 af[4], bfr[4];
#pragma unroll
            for (int t = 0; t < 4; ++t) {
                af[t]  = *(const bf16x8*)&As[0][wm + t * 16 + l16][quad * 8];
                bfr[t] = *(const bf16x8*)&Bs[0][wn + t * 16 + l16][quad * 8];
            }
#pragma unroll
            for (int mt = 0; mt < 4; ++mt)
#pragma unroll
                for (int nt = 0; nt < 4; ++nt)
                    acc[mt][nt] = __builtin_amdgcn_mfma_f32_16x16x32_bf16(
                        af[mt], bfr[nt], acc[mt][nt], 0, 0, 0);
        }
        aptr += 32;
        bptr += 32;
    }

    // epilogue: C/D layout col = lane&15, row = quad*4 + reg  [m89-verified]
    float bvals[4];
#pragma unroll
    for (int nt = 0; nt < 4; ++nt)
        bvals[nt] = bias[n0 + wn + nt * 16 + l16];

#pragma unroll
    for (int mt = 0; mt < 4; ++mt) {
        const int mbase = m0 + wm + mt * 16 + quad * 4;
#pragma unroll
        for (int nt = 0; nt < 4; ++nt) {
            const int n = n0 + wn + nt * 16 + l16;
#pragma unroll
            for (int r = 0; r < 4; ++r) {
                const float v = acc[mt][nt][r] + bvals[nt];
                const int mm  = mbase + r;
                if (MODE == 0) {
                    const int b = mm >> 11, s = mm & (SEQ - 1);
                    const int h = n >> 6, d = n & (HD - 1);
                    Out[((((size_t)b * HEADS + h) * SEQ + s) << 6) + d] = (TOut)v;
                } else {
                    Out[(size_t)mm * HID + n] = (TOut)v;
                }
            }
        }
    }
}

// ---------------------------------------------------------------------------
// Causal flash attention (unscaled logits per reference).
// TQ: dtype of Q/K workspace. SPLIT=1 (TQ=float): hi+lo QK^T (6 mfma/n-tile)
// for fp32-grade logits. V is always bf16.
// grid: (B*H, S/64). 4 waves; wave w owns q-rows [w*16, w*16+16).
// k-tiles of 64; only kt <= qt; diagonal masked with -1e30.
// P: C-layout -> LDS -> A-layout (m120). Vt[d][k] so PV B-frag is contiguous.
// ---------------------------------------------------------------------------
template <typename TQ, int SPLIT>
__global__ __launch_bounds__(256) void attn_kernel(
    const TQ* __restrict__ Q, const TQ* __restrict__ K,
    const bf16_t* __restrict__ V, bf16_t* __restrict__ O)
{
    __shared__ bf16_t Ks[SPLIT + 1][64][72];
    __shared__ bf16_t Vt[64][72];
    __shared__ bf16_t Pw[4][16][72];

    const int bh  = blockIdx.x;        // b*HEADS + h
    const int qt  = blockIdx.y;
    const int q0  = qt * 64;
    const int tid = threadIdx.x;
    const int wave = tid >> 6;
    const int lane = tid & 63;
    const int quad = lane >> 4;
    const int l16  = lane & 15;

    const TQ*     Qb = Q + (size_t)bh * SEQ * HD;
    const TQ*     Kb = K + (size_t)bh * SEQ * HD;
    const bf16_t* Vb = V + (size_t)bh * SEQ * HD;

    // Q fragments for this wave's 16 rows: A[m=lane&15][k=quad*8+j]
    bf16x8 aqh[2], aql[2];
    {
        const TQ* p = Qb + (size_t)(q0 + wave * 16 + l16) * HD + quad * 8;
        if constexpr (SPLIT) {
            split8(p, aqh[0], aql[0]);
            split8(p + 32, aqh[1], aql[1]);
        } else {
            aqh[0] = load8(p);
            aqh[1] = load8(p + 32);
        }
    }

    const floatx4 zero4 = {0.f, 0.f, 0.f, 0.f};
    floatx4 oacc[4];
#pragma unroll
    for (int dt = 0; dt < 4; ++dt) oacc[dt] = zero4;
    float mrow[4] = {-3.0e38f, -3.0e38f, -3.0e38f, -3.0e38f};
    float lrow[4] = {0.f, 0.f, 0.f, 0.f};

    const int srow = tid >> 2;         // 0..63
    const int scol = (tid & 3) * 16;   // 0,16,32,48

    for (int kt = 0; kt <= qt; ++kt) {
        const int k0 = kt * 64;
        __syncthreads();  // prior iter's LDS reads done
        {
            const TQ* ksrc = Kb + (size_t)(k0 + srow) * HD + scol;
            if constexpr (SPLIT) {
                bf16x8 h0, l0, h1, l1;
                split8(ksrc, h0, l0);
                split8(ksrc + 8, h1, l1);
                *(bf16x8*)&Ks[0][srow][scol]     = h0;
                *(bf16x8*)&Ks[0][srow][scol + 8] = h1;
                *(bf16x8*)&Ks[1][srow][scol]     = l0;
                *(bf16x8*)&Ks[1][srow][scol + 8] = l1;
            } else {
                *(bf16x8*)&Ks[0][srow][scol]     = load8(ksrc);
                *(bf16x8*)&Ks[0][srow][scol + 8] = load8(ksrc + 8);
            }
            const bf16_t* vsrc = Vb + (size_t)(k0 + srow) * HD + scol;
            bf16x8 v0 = *(const bf16x8*)vsrc;
            bf16x8 v1 = *(const bf16x8*)(vsrc + 8);
#pragma unroll
            for (int j = 0; j < 8; ++j) Vt[scol + j][srow] = v0[j];
#pragma unroll
            for (int j = 0; j < 8; ++j) Vt[scol + 8 + j][srow] = v1[j];
        }
        __syncthreads();

        // scores S[q][k]: 4 n-tiles of 16 k-cols
        floatx4 sacc[4];
#pragma unroll
        for (int nt = 0; nt < 4; ++nt) sacc[nt] = zero4;
#pragma unroll
        for (int nt = 0; nt < 4; ++nt) {
            bf16x8 b0h = *(const bf16x8*)&Ks[0][nt * 16 + l16][quad * 8];
            bf16x8 b1h = *(const bf16x8*)&Ks[0][nt * 16 + l16][quad * 8 + 32];
            sacc[nt] = __builtin_amdgcn_mfma_f32_16x16x32_bf16(aqh[0], b0h, sacc[nt], 0, 0, 0);
            sacc[nt] = __builtin_amdgcn_mfma_f32_16x16x32_bf16(aqh[1], b1h, sacc[nt], 0, 0, 0);
            if constexpr (SPLIT) {
                bf16x8 b0l = *(const bf16x8*)&Ks[1][nt * 16 + l16][quad * 8];
                bf16x8 b1l = *(const bf16x8*)&Ks[1][nt * 16 + l16][quad * 8 + 32];
                sacc[nt] = __builtin_amdgcn_mfma_f32_16x16x32_bf16(aql[0], b0h, sacc[nt], 0, 0, 0);
                sacc[nt] = __builtin_amdgcn_mfma_f32_16x16x32_bf16(aqh[0], b0l, sacc[nt], 0, 0, 0);
                sacc[nt] = __builtin_amdgcn_mfma_f32_16x16x32_bf16(aql[1], b1h, sacc[nt], 0, 0, 0);
                sacc[nt] = __builtin_amdgcn_mfma_f32_16x16x32_bf16(aqh[1], b1l, sacc[nt], 0, 0, 0);
            }
        }

        if (kt == qt) {  // diagonal tile: mask k > q (exp(-1e30 - m) == 0)
#pragma unroll
            for (int nt = 0; nt < 4; ++nt) {
                const int kidx = nt * 16 + l16;
#pragma unroll
                for (int r = 0; r < 4; ++r) {
                    const int qidx = wave * 16 + quad * 4 + r;
                    if (kidx > qidx) sacc[nt][r] = -1.0e30f;
                }
            }
        }

        // online softmax; row state replicated across the 16 lanes of a quad
        float alpha[4];
#pragma unroll
        for (int r = 0; r < 4; ++r) {
            float mx = fmaxf(fmaxf(sacc[0][r], sacc[1][r]),
                             fmaxf(sacc[2][r], sacc[3][r]));
            mx = fmaxf(mx, __shfl_xor(mx, 1));
            mx = fmaxf(mx, __shfl_xor(mx, 2));
            mx = fmaxf(mx, __shfl_xor(mx, 4));
            mx = fmaxf(mx, __shfl_xor(mx, 8));
            const float mnew = fmaxf(mrow[r], mx);
            alpha[r] = __expf(mrow[r] - mnew);
            mrow[r]  = mnew;
        }
        float rsum[4] = {0.f, 0.f, 0.f, 0.f};
#pragma unroll
        for (int nt = 0; nt < 4; ++nt)
#pragma unroll
            for (int r = 0; r < 4; ++r) {
                const float p = __expf(sacc[nt][r] - mrow[r]);
                sacc[nt][r] = p;
                rsum[r] += p;
            }
#pragma unroll
        for (int r = 0; r < 4; ++r) {
            float s = rsum[r];
            s += __shfl_xor(s, 1);
            s += __shfl_xor(s, 2);
            s += __shfl_xor(s, 4);
            s += __shfl_xor(s, 8);
            lrow[r] = lrow[r] * alpha[r] + s;
        }
#pragma unroll
        for (int dt = 0; dt < 4; ++dt)
#pragma unroll
            for (int r = 0; r < 4; ++r) oacc[dt][r] *= alpha[r];

        // P: C-layout -> LDS (bf16) -> A-layout frags
#pragma unroll
        for (int nt = 0; nt < 4; ++nt)
#pragma unroll
            for (int r = 0; r < 4; ++r)
                Pw[wave][quad * 4 + r][nt * 16 + l16] = (bf16_t)sacc[nt][r];
        __syncthreads();

#pragma unroll
        for (int s = 0; s < 2; ++s) {
            bf16x8 ap = *(const bf16x8*)&Pw[wave][l16][s * 32 + quad * 8];
#pragma unroll
            for (int dt = 0; dt < 4; ++dt) {
                bf16x8 bv = *(const bf16x8*)&Vt[dt * 16 + l16][s * 32 + quad * 8];
                oacc[dt] = __builtin_amdgcn_mfma_f32_16x16x32_bf16(ap, bv, oacc[dt], 0, 0, 0);
            }
        }
    }

    // epilogue: O[b][q][h*64+d] = oacc / l   (bf16 workspace)
    const int b = bh >> 4, h = bh & (HEADS - 1);
#pragma unroll
    for (int dt = 0; dt < 4; ++dt)
#pragma unroll
        for (int r = 0; r < 4; ++r) {
            const int q = q0 + wave * 16 + quad * 4 + r;
            const int d = h * HD + dt * 16 + l16;
            const float val = oacc[dt][r] / lrow[r];
            O[(size_t)(b * SEQ + q) * HID + d] = (bf16_t)val;
        }
}

// ---------------------------------------------------------------------------
extern "C" void kernel_launch(void* const* d_in, const int* in_sizes, int n_in,
                              void* d_out, int out_size, void* d_ws, size_t ws_size,
                              hipStream_t stream)
{
    const float* query = (const float*)d_in[0];
    const float* key   = (const float*)d_in[1];
    const float* value = (const float*)d_in[2];
    const float* Wq    = (const float*)d_in[3];
    const float* bq    = (const float*)d_in[4];
    const float* Wk    = (const float*)d_in[5];
    const float* bk    = (const float*)d_in[6];
    const float* Wv    = (const float*)d_in[7];
    const float* bv    = (const float*)d_in[8];
    const float* Wo    = (const float*)d_in[9];
    const float* bo    = (const float*)d_in[10];
    float* out = (float*)d_out;

    const size_t NE = (size_t)MTOT * HID;          // 8.39e6 elements
    const size_t needA = 2 * NE * 4 + 2 * NE * 2;  // Q,K fp32 + V,Ob bf16 = 100.7 MB

    dim3 gg(HID / 128, MTOT / 128);    // (8, 64)
    dim3 ga(BATCH * HEADS, SEQ / 64);  // (64, 32)

    if (ws_size >= needA) {
        // Path A: Q,K fp32 workspace -> fp32-grade logits end to end.
        float*  Qp = (float*)d_ws;
        float*  Kp = Qp + NE;
        bf16_t* Vp = (bf16_t*)(Kp + NE);
        bf16_t* Ob = Vp + NE;
        gemm_bt<0, 1, float, float ><<<gg, 256, 0, stream>>>(query, Wq, bq, Qp);
        gemm_bt<0, 1, float, float ><<<gg, 256, 0, stream>>>(key,   Wk, bk, Kp);
        gemm_bt<0, 0, float, bf16_t><<<gg, 256, 0, stream>>>(value, Wv, bv, Vp);
        attn_kernel<float, 1><<<ga, 256, 0, stream>>>(Qp, Kp, Vp, Ob);
        gemm_bt<1, 0, bf16_t, float><<<gg, 256, 0, stream>>>(Ob, Wo, bo, out);
    } else {
        // Path B: bf16 Q,K storage (67 MB, proven in R2). Projection split
        // still kills the dominant GEMM-rounding term; QK^T on bf16 inputs
        // is exact in the fp32 MFMA accumulator.
        bf16_t* Qp = (bf16_t*)d_ws;
        bf16_t* Kp = Qp + NE;
        bf16_t* Vp = Kp + NE;
        bf16_t* Ob = Vp + NE;
        gemm_bt<0, 1, float, bf16_t><<<gg, 256, 0, stream>>>(query, Wq, bq, Qp);
        gemm_bt<0, 1, float, bf16_t><<<gg, 256, 0, stream>>>(key,   Wk, bk, Kp);
        gemm_bt<0, 0, float, bf16_t><<<gg, 256, 0, stream>>>(value, Wv, bv, Vp);
        attn_kernel<bf16_t, 0><<<ga, 256, 0, stream>>>(Qp, Kp, Vp, Ob);
        gemm_bt<1, 0, bf16_t, float><<<gg, 256, 0, stream>>>(Ob, Wo, bo, out);
    }
}

// Round 7
// 500.351 us; speedup vs baseline: 1.0971x; 1.0971x over previous
//
#include <hip/hip_runtime.h>
#include <hip/hip_fp16.h>

typedef _Float16 half_t;
typedef half_t halfx8 __attribute__((ext_vector_type(8)));
typedef float floatx4 __attribute__((ext_vector_type(4)));

#define HID 1024
#define HEADS 16
#define HD 64
#define BATCH 4
#define SEQ 2048
#define MTOT (BATCH * SEQ) /* 8192 */

#define MFMA_F16 __builtin_amdgcn_mfma_f32_16x16x32_f16

// Load 8 contiguous elements as halfx8; fp32 source converts on the fly.
__device__ inline halfx8 load8h(const half_t* p) { return *(const halfx8*)p; }
__device__ inline halfx8 load8h(const float* p) {
    floatx4 x = *(const floatx4*)p;
    floatx4 y = *(const floatx4*)(p + 4);
    halfx8 r;
    r[0] = (half_t)x[0]; r[1] = (half_t)x[1];
    r[2] = (half_t)x[2]; r[3] = (half_t)x[3];
    r[4] = (half_t)y[0]; r[5] = (half_t)y[1];
    r[6] = (half_t)y[2]; r[7] = (half_t)y[3];
    return r;
}

// ---------------------------------------------------------------------------
// GEMM: Out = A @ W^T + bias   (A: [M,K] TA, W: [N,K] fp32, bias fp32)
// EXACT R2-proven structure; only dtype swapped bf16 -> fp16.
// MODE 0: fp16 -> [B][H][S][D]   (Q, K, V)
// MODE 1: fp32 -> flat [M, N]    (final)
// 128x128 tile, BK=32, 256 thr (4 waves 2x2), mfma 16x16x32 f16.
// LDS row stride 40 halfs = 80 B: 16B-aligned, 2-way bank alias (free).
// ---------------------------------------------------------------------------
template <int MODE, typename TA, typename TOut>
__global__ __launch_bounds__(256) void gemm_bt(
    const TA* __restrict__ A, const float* __restrict__ W,
    const float* __restrict__ bias, TOut* __restrict__ Out)
{
    __shared__ half_t As[128][40];
    __shared__ half_t Bs[128][40];

    const int tid  = threadIdx.x;
    const int m0   = blockIdx.y * 128;
    const int n0   = blockIdx.x * 128;
    const int wave = tid >> 6;
    const int lane = tid & 63;
    const int quad = lane >> 4;
    const int l16  = lane & 15;
    const int wm   = (wave >> 1) * 64;
    const int wn   = (wave & 1) * 64;
    const int trow = tid >> 1;          // 0..127
    const int tcol = (tid & 1) * 16;    // 0 or 16

    const TA*    aptr = A + (size_t)(m0 + trow) * HID + tcol;
    const float* bptr = W + (size_t)(n0 + trow) * HID + tcol;

    floatx4 acc[4][4];
    const floatx4 zero4 = {0.f, 0.f, 0.f, 0.f};
#pragma unroll
    for (int mt = 0; mt < 4; ++mt)
#pragma unroll
        for (int nt = 0; nt < 4; ++nt) acc[mt][nt] = zero4;

    for (int k0 = 0; k0 < HID; k0 += 32) {
        halfx8 av0 = load8h(aptr);
        halfx8 av1 = load8h(aptr + 8);
        halfx8 bv0 = load8h(bptr);
        halfx8 bv1 = load8h(bptr + 8);
        aptr += 32;
        bptr += 32;

        __syncthreads();  // previous iter's LDS reads done before overwrite
        *(halfx8*)&As[trow][tcol]     = av0;
        *(halfx8*)&As[trow][tcol + 8] = av1;
        *(halfx8*)&Bs[trow][tcol]     = bv0;
        *(halfx8*)&Bs[trow][tcol + 8] = bv1;
        __syncthreads();

        halfx8 af[4], bfr[4];
#pragma unroll
        for (int t = 0; t < 4; ++t) {
            af[t]  = *(const halfx8*)&As[wm + t * 16 + l16][quad * 8];
            bfr[t] = *(const halfx8*)&Bs[wn + t * 16 + l16][quad * 8];
        }
#pragma unroll
        for (int mt = 0; mt < 4; ++mt)
#pragma unroll
            for (int nt = 0; nt < 4; ++nt)
                acc[mt][nt] = MFMA_F16(af[mt], bfr[nt], acc[mt][nt], 0, 0, 0);
    }

    // epilogue: C/D layout col = lane&15, row = quad*4 + reg  [m89-verified]
    float bvals[4];
#pragma unroll
    for (int nt = 0; nt < 4; ++nt)
        bvals[nt] = bias[n0 + wn + nt * 16 + l16];

#pragma unroll
    for (int mt = 0; mt < 4; ++mt) {
        const int mbase = m0 + wm + mt * 16 + quad * 4;
#pragma unroll
        for (int nt = 0; nt < 4; ++nt) {
            const int n = n0 + wn + nt * 16 + l16;
#pragma unroll
            for (int r = 0; r < 4; ++r) {
                const float v = acc[mt][nt][r] + bvals[nt];
                const int mm  = mbase + r;
                if (MODE == 0) {
                    const int b = mm >> 11, s = mm & (SEQ - 1);
                    const int h = n >> 6, d = n & (HD - 1);
                    Out[((((size_t)b * HEADS + h) * SEQ + s) << 6) + d] = (TOut)v;
                } else {
                    Out[(size_t)mm * HID + n] = (TOut)v;
                }
            }
        }
    }
}

// ---------------------------------------------------------------------------
// Causal flash attention, fp16 in/out (unscaled logits per reference).
// EXACT R2/R3-proven structure; only dtype swapped bf16 -> fp16, no split.
// grid: (B*H, S/64). 4 waves; wave w owns q-rows [w*16, w*16+16).
// k-tiles of 64; only kt <= qt; diagonal tile masked with -1e30.
// P: C-layout -> LDS -> A-layout (m120). Vt[d][k] via in-kernel scalar
// transpose (known 2.7e7 bank conflicts -- deferred until green).
// LDS row stride 72 halfs = 144 B (16B-aligned).
// ---------------------------------------------------------------------------
__global__ __launch_bounds__(256) void attn_kernel(
    const half_t* __restrict__ Q, const half_t* __restrict__ K,
    const half_t* __restrict__ V, half_t* __restrict__ O)
{
    __shared__ half_t Ks[64][72];      // [k][d]
    __shared__ half_t Vt[64][72];      // [d][k]
    __shared__ half_t Pw[4][16][72];   // per-wave P round-trip

    const int bh  = blockIdx.x;        // b*HEADS + h
    const int qt  = blockIdx.y;
    const int q0  = qt * 64;
    const int tid = threadIdx.x;
    const int wave = tid >> 6;
    const int lane = tid & 63;
    const int quad = lane >> 4;
    const int l16  = lane & 15;

    const half_t* Qb = Q + (size_t)bh * SEQ * HD;
    const half_t* Kb = K + (size_t)bh * SEQ * HD;
    const half_t* Vb = V + (size_t)bh * SEQ * HD;

    // Q fragments for this wave's 16 rows: A[m=lane&15][k=quad*8+j]
    halfx8 aq0, aq1;
    {
        const half_t* p = Qb + (size_t)(q0 + wave * 16 + l16) * HD + quad * 8;
        aq0 = *(const halfx8*)p;
        aq1 = *(const halfx8*)(p + 32);
    }

    const floatx4 zero4 = {0.f, 0.f, 0.f, 0.f};
    floatx4 oacc[4];
#pragma unroll
    for (int dt = 0; dt < 4; ++dt) oacc[dt] = zero4;
    float mrow[4] = {-3.0e38f, -3.0e38f, -3.0e38f, -3.0e38f};
    float lrow[4] = {0.f, 0.f, 0.f, 0.f};

    const int srow = tid >> 2;         // 0..63
    const int scol = (tid & 3) * 16;   // 0,16,32,48

    for (int kt = 0; kt <= qt; ++kt) {
        const int k0 = kt * 64;
        __syncthreads();  // prior iter's Ks/Vt reads done
        {
            const half_t* ksrc = Kb + (size_t)(k0 + srow) * HD + scol;
            *(halfx8*)&Ks[srow][scol]     = *(const halfx8*)ksrc;
            *(halfx8*)&Ks[srow][scol + 8] = *(const halfx8*)(ksrc + 8);
            const half_t* vsrc = Vb + (size_t)(k0 + srow) * HD + scol;
            halfx8 v0 = *(const halfx8*)vsrc;
            halfx8 v1 = *(const halfx8*)(vsrc + 8);
#pragma unroll
            for (int j = 0; j < 8; ++j) Vt[scol + j][srow] = v0[j];
#pragma unroll
            for (int j = 0; j < 8; ++j) Vt[scol + 8 + j][srow] = v1[j];
        }
        __syncthreads();

        // scores S[q][k]: 4 n-tiles of 16 k-cols
        floatx4 sacc[4];
#pragma unroll
        for (int nt = 0; nt < 4; ++nt) sacc[nt] = zero4;
#pragma unroll
        for (int nt = 0; nt < 4; ++nt) {
            halfx8 b0 = *(const halfx8*)&Ks[nt * 16 + l16][quad * 8];
            halfx8 b1 = *(const halfx8*)&Ks[nt * 16 + l16][quad * 8 + 32];
            sacc[nt] = MFMA_F16(aq0, b0, sacc[nt], 0, 0, 0);
            sacc[nt] = MFMA_F16(aq1, b1, sacc[nt], 0, 0, 0);
        }

        if (kt == qt) {  // diagonal tile: mask k > q (exp(-1e30 - m) == 0)
#pragma unroll
            for (int nt = 0; nt < 4; ++nt) {
                const int kidx = nt * 16 + l16;
#pragma unroll
                for (int r = 0; r < 4; ++r) {
                    const int qidx = wave * 16 + quad * 4 + r;
                    if (kidx > qidx) sacc[nt][r] = -1.0e30f;
                }
            }
        }

        // online softmax; row state replicated across the 16 lanes of a quad
        float alpha[4];
#pragma unroll
        for (int r = 0; r < 4; ++r) {
            float mx = fmaxf(fmaxf(sacc[0][r], sacc[1][r]),
                             fmaxf(sacc[2][r], sacc[3][r]));
            mx = fmaxf(mx, __shfl_xor(mx, 1));
            mx = fmaxf(mx, __shfl_xor(mx, 2));
            mx = fmaxf(mx, __shfl_xor(mx, 4));
            mx = fmaxf(mx, __shfl_xor(mx, 8));
            const float mnew = fmaxf(mrow[r], mx);
            alpha[r] = __expf(mrow[r] - mnew);
            mrow[r]  = mnew;
        }
        float rsum[4] = {0.f, 0.f, 0.f, 0.f};
#pragma unroll
        for (int nt = 0; nt < 4; ++nt)
#pragma unroll
            for (int r = 0; r < 4; ++r) {
                const float p = __expf(sacc[nt][r] - mrow[r]);
                sacc[nt][r] = p;
                rsum[r] += p;
            }
#pragma unroll
        for (int r = 0; r < 4; ++r) {
            float s = rsum[r];
            s += __shfl_xor(s, 1);
            s += __shfl_xor(s, 2);
            s += __shfl_xor(s, 4);
            s += __shfl_xor(s, 8);
            lrow[r] = lrow[r] * alpha[r] + s;
        }
#pragma unroll
        for (int dt = 0; dt < 4; ++dt)
#pragma unroll
            for (int r = 0; r < 4; ++r) oacc[dt][r] *= alpha[r];

        // P: C-layout -> LDS (fp16) -> A-layout frags
#pragma unroll
        for (int nt = 0; nt < 4; ++nt)
#pragma unroll
            for (int r = 0; r < 4; ++r)
                Pw[wave][quad * 4 + r][nt * 16 + l16] = (half_t)sacc[nt][r];
        __syncthreads();

#pragma unroll
        for (int s = 0; s < 2; ++s) {
            halfx8 ap = *(const halfx8*)&Pw[wave][l16][s * 32 + quad * 8];
#pragma unroll
            for (int dt = 0; dt < 4; ++dt) {
                halfx8 bv = *(const halfx8*)&Vt[dt * 16 + l16][s * 32 + quad * 8];
                oacc[dt] = MFMA_F16(ap, bv, oacc[dt], 0, 0, 0);
            }
        }
    }

    // epilogue: O[b][q][h*64+d] = oacc / l   (fp16 workspace)
    const int b = bh >> 4, h = bh & (HEADS - 1);
#pragma unroll
    for (int dt = 0; dt < 4; ++dt)
#pragma unroll
        for (int r = 0; r < 4; ++r) {
            const int q = q0 + wave * 16 + quad * 4 + r;
            const int d = h * HD + dt * 16 + l16;
            const float val = oacc[dt][r] / lrow[r];
            O[(size_t)(b * SEQ + q) * HID + d] = (half_t)val;
        }
}

// ---------------------------------------------------------------------------
extern "C" void kernel_launch(void* const* d_in, const int* in_sizes, int n_in,
                              void* d_out, int out_size, void* d_ws, size_t ws_size,
                              hipStream_t stream)
{
    const float* query = (const float*)d_in[0];
    const float* key   = (const float*)d_in[1];
    const float* value = (const float*)d_in[2];
    const float* Wq    = (const float*)d_in[3];
    const float* bq    = (const float*)d_in[4];
    const float* Wk    = (const float*)d_in[5];
    const float* bk    = (const float*)d_in[6];
    const float* Wv    = (const float*)d_in[7];
    const float* bv    = (const float*)d_in[8];
    const float* Wo    = (const float*)d_in[9];
    const float* bo    = (const float*)d_in[10];
    float* out = (float*)d_out;

    // workspace (fp16): Qp, Kp, Vp [B][H][S][D]; Ob [M][HID].
    // Total 4 * NE * 2 B = 67.1 MB -- the R2-proven ws_size bound.
    const size_t NE = (size_t)MTOT * HID;
    half_t* Qp = (half_t*)d_ws;
    half_t* Kp = Qp + NE;
    half_t* Vp = Kp + NE;
    half_t* Ob = Vp + NE;

    dim3 gg(HID / 128, MTOT / 128);    // (8, 64)
    gemm_bt<0, float, half_t><<<gg, 256, 0, stream>>>(query, Wq, bq, Qp);
    gemm_bt<0, float, half_t><<<gg, 256, 0, stream>>>(key,   Wk, bk, Kp);
    gemm_bt<0, float, half_t><<<gg, 256, 0, stream>>>(value, Wv, bv, Vp);

    dim3 ga(BATCH * HEADS, SEQ / 64);  // (64, 32)
    attn_kernel<<<ga, 256, 0, stream>>>(Qp, Kp, Vp, Ob);

    gemm_bt<1, half_t, float><<<gg, 256, 0, stream>>>(Ob, Wo, bo, out);
}

// Round 8
// 470.030 us; speedup vs baseline: 1.1679x; 1.0645x over previous
//
#include <hip/hip_runtime.h>
#include <hip/hip_fp16.h>

typedef _Float16 half_t;
typedef half_t halfx8 __attribute__((ext_vector_type(8)));
typedef half_t halfx4 __attribute__((ext_vector_type(4)));
typedef float floatx4 __attribute__((ext_vector_type(4)));

#define HID 1024
#define HEADS 16
#define HD 64
#define BATCH 4
#define SEQ 2048
#define MTOT (BATCH * SEQ) /* 8192 */

#define MFMA_F16 __builtin_amdgcn_mfma_f32_16x16x32_f16

// Load 8 contiguous elements as halfx8; fp32 source converts on the fly.
__device__ inline halfx8 load8h(const half_t* p) { return *(const halfx8*)p; }
__device__ inline halfx8 load8h(const float* p) {
    floatx4 x = *(const floatx4*)p;
    floatx4 y = *(const floatx4*)(p + 4);
    halfx8 r;
    r[0] = (half_t)x[0]; r[1] = (half_t)x[1];
    r[2] = (half_t)x[2]; r[3] = (half_t)x[3];
    r[4] = (half_t)y[0]; r[5] = (half_t)y[1];
    r[6] = (half_t)y[2]; r[7] = (half_t)y[3];
    return r;
}

// ---------------------------------------------------------------------------
// GEMM: Out = A @ W^T + bias   (A: [M,K] TA, W: [N,K] fp32, bias fp32)
// R7-proven structure (fp16 MFMA, fp32->fp16 staging cvt).
// MODE 0: fp16 -> [B][H][S][D]   (Q, K)
// MODE 1: fp32 -> flat [M, N]    (final)
// MODE 2: fp16 -> [B][H][D][S]   (V transposed; 8B-aligned halfx4 stores)
// 128x128 tile, BK=32, 256 thr (4 waves 2x2), mfma 16x16x32 f16.
// ---------------------------------------------------------------------------
template <int MODE, typename TA, typename TOut>
__global__ __launch_bounds__(256) void gemm_bt(
    const TA* __restrict__ A, const float* __restrict__ W,
    const float* __restrict__ bias, TOut* __restrict__ Out)
{
    __shared__ half_t As[128][40];
    __shared__ half_t Bs[128][40];

    const int tid  = threadIdx.x;
    const int m0   = blockIdx.y * 128;
    const int n0   = blockIdx.x * 128;
    const int wave = tid >> 6;
    const int lane = tid & 63;
    const int quad = lane >> 4;
    const int l16  = lane & 15;
    const int wm   = (wave >> 1) * 64;
    const int wn   = (wave & 1) * 64;
    const int trow = tid >> 1;          // 0..127
    const int tcol = (tid & 1) * 16;    // 0 or 16

    const TA*    aptr = A + (size_t)(m0 + trow) * HID + tcol;
    const float* bptr = W + (size_t)(n0 + trow) * HID + tcol;

    floatx4 acc[4][4];
    const floatx4 zero4 = {0.f, 0.f, 0.f, 0.f};
#pragma unroll
    for (int mt = 0; mt < 4; ++mt)
#pragma unroll
        for (int nt = 0; nt < 4; ++nt) acc[mt][nt] = zero4;

    for (int k0 = 0; k0 < HID; k0 += 32) {
        halfx8 av0 = load8h(aptr);
        halfx8 av1 = load8h(aptr + 8);
        halfx8 bv0 = load8h(bptr);
        halfx8 bv1 = load8h(bptr + 8);
        aptr += 32;
        bptr += 32;

        __syncthreads();  // previous iter's LDS reads done before overwrite
        *(halfx8*)&As[trow][tcol]     = av0;
        *(halfx8*)&As[trow][tcol + 8] = av1;
        *(halfx8*)&Bs[trow][tcol]     = bv0;
        *(halfx8*)&Bs[trow][tcol + 8] = bv1;
        __syncthreads();

        halfx8 af[4], bfr[4];
#pragma unroll
        for (int t = 0; t < 4; ++t) {
            af[t]  = *(const halfx8*)&As[wm + t * 16 + l16][quad * 8];
            bfr[t] = *(const halfx8*)&Bs[wn + t * 16 + l16][quad * 8];
        }
#pragma unroll
        for (int mt = 0; mt < 4; ++mt)
#pragma unroll
            for (int nt = 0; nt < 4; ++nt)
                acc[mt][nt] = MFMA_F16(af[mt], bfr[nt], acc[mt][nt], 0, 0, 0);
    }

    // epilogue: C/D layout col = lane&15, row = quad*4 + reg  [m89-verified]
    float bvals[4];
#pragma unroll
    for (int nt = 0; nt < 4; ++nt)
        bvals[nt] = bias[n0 + wn + nt * 16 + l16];

#pragma unroll
    for (int mt = 0; mt < 4; ++mt) {
        const int mbase = m0 + wm + mt * 16 + quad * 4;
#pragma unroll
        for (int nt = 0; nt < 4; ++nt) {
            const int n = n0 + wn + nt * 16 + l16;
            if (MODE == 2) {
                const int b = mbase >> 11, s = mbase & (SEQ - 1);
                const int h = n >> 6, d = n & (HD - 1);
                halfx4 st;
#pragma unroll
                for (int r = 0; r < 4; ++r)
                    st[r] = (half_t)(acc[mt][nt][r] + bvals[nt]);
                *(halfx4*)((half_t*)Out +
                    ((((size_t)b * HEADS + h) * HD + d) << 11) + s) = st;
            } else {
#pragma unroll
                for (int r = 0; r < 4; ++r) {
                    const float v = acc[mt][nt][r] + bvals[nt];
                    const int mm  = mbase + r;
                    if (MODE == 0) {
                        const int b = mm >> 11, s = mm & (SEQ - 1);
                        const int h = n >> 6, d = n & (HD - 1);
                        Out[((((size_t)b * HEADS + h) * SEQ + s) << 6) + d] = (TOut)v;
                    } else {
                        Out[(size_t)mm * HID + n] = (TOut)v;
                    }
                }
            }
        }
    }
}

// ---------------------------------------------------------------------------
// Causal flash attention, fp16 (unscaled logits per reference).
// grid: (B*H, S/128). Block 256 thr / 4 waves; wave w owns q-rows
// [q0+w*32, +32) (2 m-tiles). k-tiles of 64; ktiles = 2*qt+2; fully-masked
// tiles predicated off (barriers stay uniform). V arrives pre-transposed
// [b][h][d][s].
// STAGING COVERAGE (the R4-R6 bug): tile = 64x64 halfs = 4096; 256 threads
// must stage 16 halfs each = TWO halfx8 stores (one store = half the tile
// uninitialized -> NaN).
// LDS row stride 72 halfs = 144 B (16B-aligned; 2-way alias free).
// ---------------------------------------------------------------------------
__global__ __launch_bounds__(256) void attn_kernel(
    const half_t* __restrict__ Q, const half_t* __restrict__ K,
    const half_t* __restrict__ VT, half_t* __restrict__ O)
{
    __shared__ half_t Ks[64][72];      // [k][d]
    __shared__ half_t Vt[64][72];      // [d][k]
    __shared__ half_t Pw[4][32][72];   // per-wave P round-trip

    const int bh  = blockIdx.x;                      // b*HEADS + h
    const int qt  = (gridDim.y - 1) - blockIdx.y;    // heaviest tiles first
    const int q0  = qt * 128;
    const int tid = threadIdx.x;
    const int wave = tid >> 6;
    const int lane = tid & 63;
    const int quad = lane >> 4;
    const int l16  = lane & 15;

    const half_t* Qb  = Q  + (size_t)bh * SEQ * HD;
    const half_t* Kb  = K  + (size_t)bh * SEQ * HD;
    const half_t* VTb = VT + (size_t)bh * HD * SEQ;

    // Q fragments: A[m=lane&15][k=quad*8+j], 2 m-tiles x 2 k-halves
    halfx8 aq[2][2];
#pragma unroll
    for (int mt = 0; mt < 2; ++mt) {
        const half_t* p = Qb + (size_t)(q0 + wave * 32 + mt * 16 + l16) * HD + quad * 8;
        aq[mt][0] = *(const halfx8*)p;
        aq[mt][1] = *(const halfx8*)(p + 32);
    }

    const floatx4 zero4 = {0.f, 0.f, 0.f, 0.f};
    floatx4 oacc[2][4];
    float mrow[2][4], lrow[2][4];
#pragma unroll
    for (int mt = 0; mt < 2; ++mt)
#pragma unroll
        for (int i = 0; i < 4; ++i) {
            oacc[mt][i] = zero4;
            mrow[mt][i] = -3.0e38f;
            lrow[mt][i] = 0.f;
        }

    const int srow = tid >> 2;         // 0..63
    const int scol = (tid & 3) * 16;   // 0,16,32,48
    const int ktiles = 2 * qt + 2;

    for (int kt = 0; kt < ktiles; ++kt) {
        const int k0 = kt * 64;
        __syncthreads();  // prior iter's Ks/Vt reads done
        {
            const half_t* ksrc = Kb + (size_t)(k0 + srow) * HD + scol;
            *(halfx8*)&Ks[srow][scol]     = *(const halfx8*)ksrc;
            *(halfx8*)&Ks[srow][scol + 8] = *(const halfx8*)(ksrc + 8);
            const half_t* vsrc = VTb + (size_t)srow * SEQ + k0 + scol;
            *(halfx8*)&Vt[srow][scol]     = *(const halfx8*)vsrc;
            *(halfx8*)&Vt[srow][scol + 8] = *(const halfx8*)(vsrc + 8);
        }
        __syncthreads();

        // wave-uniform activity predicate (no continue: barriers stay uniform)
        const bool active = (k0 <= q0 + wave * 32 + 31);

        if (active) {
            // scores S[q][k]
            floatx4 sacc[2][4];
#pragma unroll
            for (int mt = 0; mt < 2; ++mt)
#pragma unroll
                for (int nt = 0; nt < 4; ++nt) sacc[mt][nt] = zero4;
#pragma unroll
            for (int nt = 0; nt < 4; ++nt) {
                halfx8 bk0 = *(const halfx8*)&Ks[nt * 16 + l16][quad * 8];
                halfx8 bk1 = *(const halfx8*)&Ks[nt * 16 + l16][quad * 8 + 32];
#pragma unroll
                for (int mt = 0; mt < 2; ++mt) {
                    sacc[mt][nt] = MFMA_F16(aq[mt][0], bk0, sacc[mt][nt], 0, 0, 0);
                    sacc[mt][nt] = MFMA_F16(aq[mt][1], bk1, sacc[mt][nt], 0, 0, 0);
                }
            }

            if (kt >= 2 * qt) {  // diagonal region: mask k > q
#pragma unroll
                for (int mt = 0; mt < 2; ++mt)
#pragma unroll
                    for (int nt = 0; nt < 4; ++nt) {
                        const int kg = k0 + nt * 16 + l16;
#pragma unroll
                        for (int r = 0; r < 4; ++r) {
                            const int qg = q0 + wave * 32 + mt * 16 + quad * 4 + r;
                            if (kg > qg) sacc[mt][nt][r] = -1.0e30f;
                        }
                    }
            }

            // online softmax; row state replicated across 16 lanes of a quad
#pragma unroll
            for (int mt = 0; mt < 2; ++mt) {
                float alpha[4];
#pragma unroll
                for (int r = 0; r < 4; ++r) {
                    float mx = fmaxf(fmaxf(sacc[mt][0][r], sacc[mt][1][r]),
                                     fmaxf(sacc[mt][2][r], sacc[mt][3][r]));
                    mx = fmaxf(mx, __shfl_xor(mx, 1));
                    mx = fmaxf(mx, __shfl_xor(mx, 2));
                    mx = fmaxf(mx, __shfl_xor(mx, 4));
                    mx = fmaxf(mx, __shfl_xor(mx, 8));
                    const float mnew = fmaxf(mrow[mt][r], mx);
                    alpha[r]    = __expf(mrow[mt][r] - mnew);
                    mrow[mt][r] = mnew;
                }
                float rsum[4] = {0.f, 0.f, 0.f, 0.f};
#pragma unroll
                for (int nt = 0; nt < 4; ++nt)
#pragma unroll
                    for (int r = 0; r < 4; ++r) {
                        const float p = __expf(sacc[mt][nt][r] - mrow[mt][r]);
                        sacc[mt][nt][r] = p;
                        rsum[r] += p;
                    }
#pragma unroll
                for (int r = 0; r < 4; ++r) {
                    float s = rsum[r];
                    s += __shfl_xor(s, 1);
                    s += __shfl_xor(s, 2);
                    s += __shfl_xor(s, 4);
                    s += __shfl_xor(s, 8);
                    lrow[mt][r] = lrow[mt][r] * alpha[r] + s;
                }
#pragma unroll
                for (int dt = 0; dt < 4; ++dt)
#pragma unroll
                    for (int r = 0; r < 4; ++r) oacc[mt][dt][r] *= alpha[r];

                // P: C-layout -> LDS
#pragma unroll
                for (int nt = 0; nt < 4; ++nt)
#pragma unroll
                    for (int r = 0; r < 4; ++r)
                        Pw[wave][mt * 16 + quad * 4 + r][nt * 16 + l16] =
                            (half_t)sacc[mt][nt][r];
            }
        }

        __syncthreads();  // P write -> PV read (uniform barrier)

        if (active) {
            // PV: A = P (LDS round trip), B = Vt
#pragma unroll
            for (int s2 = 0; s2 < 2; ++s2) {
                halfx8 ap0 = *(const halfx8*)&Pw[wave][l16][s2 * 32 + quad * 8];
                halfx8 ap1 = *(const halfx8*)&Pw[wave][16 + l16][s2 * 32 + quad * 8];
#pragma unroll
                for (int dt = 0; dt < 4; ++dt) {
                    halfx8 bv = *(const halfx8*)&Vt[dt * 16 + l16][s2 * 32 + quad * 8];
                    oacc[0][dt] = MFMA_F16(ap0, bv, oacc[0][dt], 0, 0, 0);
                    oacc[1][dt] = MFMA_F16(ap1, bv, oacc[1][dt], 0, 0, 0);
                }
            }
        }
    }

    // epilogue: Ob[b][q][h*64+d] = oacc / l   (fp16 workspace)
    const int b = bh >> 4, h = bh & (HEADS - 1);
#pragma unroll
    for (int mt = 0; mt < 2; ++mt)
#pragma unroll
        for (int dt = 0; dt < 4; ++dt)
#pragma unroll
            for (int r = 0; r < 4; ++r) {
                const int q = q0 + wave * 32 + mt * 16 + quad * 4 + r;
                const int d = h * HD + dt * 16 + l16;
                O[(size_t)(b * SEQ + q) * HID + d] =
                    (half_t)(oacc[mt][dt][r] / lrow[mt][r]);
            }
}

// ---------------------------------------------------------------------------
extern "C" void kernel_launch(void* const* d_in, const int* in_sizes, int n_in,
                              void* d_out, int out_size, void* d_ws, size_t ws_size,
                              hipStream_t stream)
{
    const float* query = (const float*)d_in[0];
    const float* key   = (const float*)d_in[1];
    const float* value = (const float*)d_in[2];
    const float* Wq    = (const float*)d_in[3];
    const float* bq    = (const float*)d_in[4];
    const float* Wk    = (const float*)d_in[5];
    const float* bk    = (const float*)d_in[6];
    const float* Wv    = (const float*)d_in[7];
    const float* bv    = (const float*)d_in[8];
    const float* Wo    = (const float*)d_in[9];
    const float* bo    = (const float*)d_in[10];
    float* out = (float*)d_out;

    // workspace (fp16): Qp, Kp [B][H][S][D]; VpT [B][H][D][S]; Ob [M][HID].
    // Total 4 * NE * 2 B = 67.1 MB -- the R2-proven ws_size bound.
    const size_t NE = (size_t)MTOT * HID;
    half_t* Qp  = (half_t*)d_ws;
    half_t* Kp  = Qp  + NE;
    half_t* VpT = Kp  + NE;
    half_t* Ob  = VpT + NE;

    dim3 gg(HID / 128, MTOT / 128);    // (8, 64)
    gemm_bt<0, float, half_t><<<gg, 256, 0, stream>>>(query, Wq, bq, Qp);
    gemm_bt<0, float, half_t><<<gg, 256, 0, stream>>>(key,   Wk, bk, Kp);
    gemm_bt<2, float, half_t><<<gg, 256, 0, stream>>>(value, Wv, bv, VpT);

    dim3 ga(BATCH * HEADS, SEQ / 128);  // (64, 16)
    attn_kernel<<<ga, 256, 0, stream>>>(Qp, Kp, VpT, Ob);

    gemm_bt<1, half_t, float><<<gg, 256, 0, stream>>>(Ob, Wo, bo, out);
}